// Round 3
// 395.782 us; speedup vs baseline: 1.1753x; 1.1753x over previous
//
#include <hip/hip_runtime.h>
#include <hip/hip_bf16.h>

typedef __hip_bfloat16 bf16;
typedef __attribute__((ext_vector_type(8))) short short8;   // 8 bf16 = 4 VGPRs
typedef __attribute__((ext_vector_type(4))) float float4v;  // MFMA C/D
typedef __attribute__((ext_vector_type(4))) short short4v;

__device__ __forceinline__ short f2bs(float x) {
    bf16 b = __float2bfloat16(x);
    return *reinterpret_cast<short*>(&b);
}
__device__ __forceinline__ float bs2f(short s) {
    bf16 b = *reinterpret_cast<bf16*>(&s);
    return __bfloat162float(b);
}

#define GLL16(g, l) __builtin_amdgcn_global_load_lds(                      \
    (const __attribute__((address_space(1))) void*)(g),                    \
    (__attribute__((address_space(3))) void*)(l), 16, 0, 0)

// ---------------- preprocessing: f32 -> padded bf16 layouts ----------------

// emb (50000,300) f32 -> emb_bf (50000,320) bf16, zero pad. 4 shorts/thread.
__global__ __launch_bounds__(256) void conv_emb(
    const float* __restrict__ src, short* __restrict__ dst)
{
    const int idx = blockIdx.x * 256 + threadIdx.x;      // 50000*80
    if (idx >= 50000 * 80) return;
    const int row = idx / 80;
    const int k4  = (idx - row * 80) * 4;
    short4v v;
#pragma unroll
    for (int j = 0; j < 4; ++j)
        v[j] = (k4 + j < 300) ? f2bs(src[(long)row * 300 + k4 + j]) : (short)0;
    *(short4v*)&dst[(long)row * 320 + k4] = v;
}

// W_leaf (300,300) -> Bleaf (320,320) bf16 zero-padded
__global__ __launch_bounds__(256) void conv_wleaf(
    const float* __restrict__ src, short* __restrict__ dst)
{
    const int idx = blockIdx.x * 256 + threadIdx.x;      // 320*320
    if (idx >= 320 * 320) return;
    const int row = idx / 320, k = idx - row * 320;
    dst[idx] = (row < 300 && k < 300) ? f2bs(src[row * 300 + k]) : (short)0;
}

// W_h (300,600) -> Bh (320,640): k'<300 -> k'; 320<=k'<620 -> k'-20; else 0
__global__ __launch_bounds__(256) void conv_wh(
    const float* __restrict__ src, short* __restrict__ dst)
{
    const int idx = blockIdx.x * 256 + threadIdx.x;      // 320*640
    if (idx >= 320 * 640) return;
    const int row = idx / 640, k = idx - row * 640;
    float v = 0.f;
    if (row < 300) {
        if (k < 300)                 v = src[row * 600 + k];
        else if (k >= 320 && k < 620) v = src[row * 600 + k - 20];
    }
    dst[idx] = f2bs(v);
}

// b_h (300,) -> biasp (320,) f32 zero-padded
__global__ __launch_bounds__(320) void conv_bias(
    const float* __restrict__ src, float* __restrict__ dst)
{
    const int i = threadIdx.x;
    if (i < 320) dst[i] = (i < 300) ? src[i] : 0.f;
}

// ---------------- MFMA GEMM ----------------
// out(M,320 bf16) = X(M,KE bf16) @ Wp(320,KE bf16)^T (+ biasp), KE in {320,640}.
// GMODE 0: X read directly from Xsrc rows.
// GMODE 2 (KE=640 only): A-row m = concat(Hv[wid[2m]], Hv[wid[2m+1]]) gathered
//   from the vocab-level table `emb` (640 B per gathered half-row).
// Block: 256 thr = 4 waves 2x2; tile M=128 x N=320 (full N). Wave: 64x160 =
// 4 M-tiles x 10 N-tiles of v_mfma_f32_16x16x32_bf16. Single-buffer LDS,
// global_load_lds width=16 staging, XOR k-quarter swizzle (2-way banks = free).
template <int KE, int GMODE, bool BIAS>
__global__ __launch_bounds__(256, 2) void mfma_gemm(
    const short* __restrict__ Xsrc, const int* __restrict__ wid,
    const short* __restrict__ emb, const short* __restrict__ Wp,
    const float* __restrict__ biasp, short* __restrict__ out)
{
    static_assert(GMODE != 2 || KE == 640, "pair-gather requires KE=640");
    __shared__ __align__(16) short As[128 * 32];   // [row][kq-slot] 64B rows
    __shared__ __align__(16) short Bs[320 * 32];

    const int tid  = threadIdx.x;
    const int lane = tid & 63;
    const int w    = tid >> 6;
    const int wm   = w >> 1, wn = w & 1;
    const long m0  = (long)blockIdx.x * 128;

    const int s_q   = lane & 3;     // this lane's LDS k-quarter slot
    const int r_off = lane >> 2;    // row within 16-row staging group

    // staging global pointers (chunk-invariant bases)
    const char* gL[2];
    const char* gR[2];
#pragma unroll
    for (int j = 0; j < 2; ++j) {
        const int r = (w * 2 + j) * 16 + r_off;            // 0..127
        const int q = s_q ^ ((r >> 1) & 3);                // global k-quarter
        if (GMODE == 2) {
            const long node = m0 + r;
            gL[j] = (const char*)emb + (long)wid[2 * node]     * 640 + q * 16;
            gR[j] = (const char*)emb + (long)wid[2 * node + 1] * 640 + q * 16;
        } else {
            gL[j] = (const char*)Xsrc + (m0 + r) * (long)(KE * 2) + q * 16;
            gR[j] = gL[j];
        }
    }
    const char* gB[5];
#pragma unroll
    for (int j = 0; j < 5; ++j) {
        const int r = (w * 5 + j) * 16 + r_off;            // 0..319
        const int q = s_q ^ ((r >> 1) & 3);
        gB[j] = (const char*)Wp + r * (long)(KE * 2) + q * 16;
    }
    // LDS destinations (wave-uniform base; HW scatters lane*16)
    char* lA[2]; char* lB[5];
#pragma unroll
    for (int j = 0; j < 2; ++j) lA[j] = (char*)As + (w * 2 + j) * 1024;
#pragma unroll
    for (int j = 0; j < 5; ++j) lB[j] = (char*)Bs + (w * 5 + j) * 1024;

    // fragment LDS addresses (single buffer -> chunk-invariant)
    const short* fA[4];
#pragma unroll
    for (int t = 0; t < 4; ++t) {
        const int row = wm * 64 + t * 16 + (lane & 15);
        const int s   = (lane >> 4) ^ ((row >> 1) & 3);
        fA[t] = &As[row * 32 + s * 8];
    }
    const short* fB[10];
#pragma unroll
    for (int u = 0; u < 10; ++u) {
        const int n = wn * 160 + u * 16 + (lane & 15);
        const int s = (lane >> 4) ^ ((n >> 1) & 3);
        fB[u] = &Bs[n * 32 + s * 8];
    }

    float4v acc[4][10];
#pragma unroll
    for (int t = 0; t < 4; ++t)
#pragma unroll
        for (int u = 0; u < 10; ++u) acc[t][u] = (float4v)0.f;

    const int NCH = KE / 32;
    for (int kc = 0; kc < NCH; ++kc) {
        if (kc) __syncthreads();           // all waves done reading prev chunk
        if (GMODE == 2) {
            // chunks 0..9 = left gathered row, 10..19 = right gathered row
            const bool lft = (kc < 10);
            const int off = (lft ? kc : kc - 10) * 64;
            GLL16((lft ? gL[0] : gR[0]) + off, lA[0]);
            GLL16((lft ? gL[1] : gR[1]) + off, lA[1]);
        } else {
            const int off = kc * 64;
            GLL16(gL[0] + off, lA[0]);
            GLL16(gL[1] + off, lA[1]);
        }
        const int offb = kc * 64;
        GLL16(gB[0] + offb, lB[0]);
        GLL16(gB[1] + offb, lB[1]);
        GLL16(gB[2] + offb, lB[2]);
        GLL16(gB[3] + offb, lB[3]);
        GLL16(gB[4] + offb, lB[4]);
        __syncthreads();                   // drains vmcnt -> LDS visible

        short8 a[4], b[10];
#pragma unroll
        for (int t = 0; t < 4; ++t) a[t] = *(const short8*)fA[t];
#pragma unroll
        for (int u = 0; u < 10; ++u) b[u] = *(const short8*)fB[u];
#pragma unroll
        for (int u = 0; u < 10; ++u)
#pragma unroll
            for (int t = 0; t < 4; ++t)
                acc[t][u] = __builtin_amdgcn_mfma_f32_16x16x32_bf16(
                    a[t], b[u], acc[t][u], 0, 0, 0);
    }

    // epilogue: C/D layout col=lane&15, row=(lane>>4)*4+reg
#pragma unroll
    for (int u = 0; u < 10; ++u) {
        const int c = wn * 160 + u * 16 + (lane & 15);
        const float bv = BIAS ? biasp[c] : 0.f;
#pragma unroll
        for (int t = 0; t < 4; ++t) {
            const long mb = m0 + wm * 64 + t * 16 + (lane >> 4) * 4;
#pragma unroll
            for (int r4 = 0; r4 < 4; ++r4)
                out[(mb + r4) * 320 + c] = f2bs(acc[t][u][r4] + bv);
        }
    }
}

// ---------------- classifier ----------------
// roots: 512 rows of 640 bf16 (pads at 300..320, 620..640). One wave per row.
__global__ __launch_bounds__(64) void cls_kernel(
    const short* __restrict__ roots, const float* __restrict__ W_cls,
    const float* __restrict__ b_cls, float* __restrict__ out)
{
    const int b    = blockIdx.x;
    const int lane = threadIdx.x;
    const short* row = roots + (long)b * 640;

    float a0 = 0.f, a1 = 0.f, a2 = 0.f;
#pragma unroll
    for (int i = 0; i < 10; ++i) {
        const int k = lane + 64 * i;
        if (k < 600) {
            const int col = (k < 300) ? k : k + 20;
            const float f = 1.f / (1.f + __expf(-bs2f(row[col])));
            a0 += f * W_cls[k];
            a1 += f * W_cls[600 + k];
            a2 += f * W_cls[1200 + k];
        }
    }
#pragma unroll
    for (int off = 32; off > 0; off >>= 1) {
        a0 += __shfl_down(a0, off);
        a1 += __shfl_down(a1, off);
        a2 += __shfl_down(a2, off);
    }
    if (lane == 0) {
        const float l0 = a0 + b_cls[0];
        const float l1 = a1 + b_cls[1];
        const float l2 = a2 + b_cls[2];
        const float m  = fmaxf(l0, fmaxf(l1, l2));
        const float s  = __expf(l0 - m) + __expf(l1 - m) + __expf(l2 - m);
        const float ls = m + __logf(s);
        out[b * 3 + 0] = l0 - ls;
        out[b * 3 + 1] = l1 - ls;
        out[b * 3 + 2] = l2 - ls;
    }
}

extern "C" void kernel_launch(void* const* d_in, const int* in_sizes, int n_in,
                              void* d_out, int out_size, void* d_ws, size_t ws_size,
                              hipStream_t stream)
{
    const int*   wid    = (const int*)d_in[0];     // (512,2,256) int32
    const float* emb    = (const float*)d_in[1];   // (50000,300) f32
    const float* W_leaf = (const float*)d_in[2];   // (300,300)
    const float* W_h    = (const float*)d_in[3];   // (300,600)
    const float* b_h    = (const float*)d_in[4];   // (300,)
    const float* W_cls  = (const float*)d_in[5];   // (3,600)
    const float* b_cls  = (const float*)d_in[6];   // (3,)
    float* outp = (float*)d_out;                   // (512,3) f32

    (void)in_sizes; (void)n_in; (void)out_size; (void)ws_size;

    // ws layout (peak 158,475,520 B):
    //   bufA   @ 0           : 131072*320*2 =  83,886,080  (tree ping)
    //   bufB   @  83,886,080 :  65536*320*2 =  41,943,040  (tree pong)
    //   emb_bf @  83,886,080 : 50048*320*2  =  32,030,720  (ALIASES bufB: dead
    //            after Hv GEMM; bufB first written at L2, which runs later)
    //   Hv     @ 125,829,120 : 50048*320*2  =  32,030,720  (vocab leaf hidden)
    //   Bleaf  @ 157,859,840 : 320*320*2    =     204,800
    //   Bh     @ 158,064,640 : 320*640*2    =     409,600
    //   biasp  @ 158,474,240 : 320*4        =       1,280
    char* ws = (char*)d_ws;
    short* bufA   = (short*)(ws);
    short* bufB   = (short*)(ws + 83886080);
    short* emb_bf = (short*)(ws + 83886080);
    short* Hv     = (short*)(ws + 125829120);
    short* Bleaf  = (short*)(ws + 157859840);
    short* Bh     = (short*)(ws + 158064640);
    float* biasp  = (float*)(ws + 158474240);

    conv_emb  <<<(50000 * 80 + 255) / 256, 256, 0, stream>>>(emb, emb_bf);
    conv_wleaf<<<(320 * 320) / 256, 256, 0, stream>>>(W_leaf, Bleaf);
    conv_wh   <<<(320 * 640) / 256, 256, 0, stream>>>(W_h, Bh);
    conv_bias <<<1, 320, 0, stream>>>(b_h, biasp);

    // Vocab-level leaf transform: Hv = emb_bf @ Bleaf^T, M=50048 (391 blocks).
    // Rows 50000..50047 are garbage (never gathered). 10.2 GF vs the old
    // 53.7 GF per-leaf GEMM; kills the 168 MB hA HBM round-trip entirely.
    mfma_gemm<320, 0, false><<<50048 / 128, 256, 0, stream>>>(
        emb_bf, nullptr, nullptr, Bleaf, biasp, Hv);

    // L1: node m = W_h @ concat(Hv[wid[2m]], Hv[wid[2m+1]]) + b_h.
    // Gathered 640 B half-rows; Hv (32 MB) is L3-resident. K' = 640.
    mfma_gemm<640, 2, true><<<131072 / 128, 256, 0, stream>>>(
        nullptr, wid, Hv, Bh, biasp, bufA);

    // L2..L8: node m reads prev rows 2m,2m+1 = contiguous 640 bf16 (pads align
    // with Bh's zero k-columns). Ping-pong bufA <-> bufB.
    short* cur = bufA;
    short* nxt = bufB;
    int nodes = 65536;
    for (int l = 0; l < 7; ++l) {
        mfma_gemm<640, 0, true><<<nodes / 128, 256, 0, stream>>>(
            cur, nullptr, nullptr, Bh, biasp, nxt);
        short* t = cur; cur = nxt; nxt = t;
        nodes >>= 1;
    }
    // roots: cur holds 1024 rows x 320 -> 512 x 640 view

    cls_kernel<<<512, 64, 0, stream>>>(cur, W_cls, b_cls, outp);
}

// Round 4
// 382.866 us; speedup vs baseline: 1.2149x; 1.0337x over previous
//
#include <hip/hip_runtime.h>
#include <hip/hip_bf16.h>

typedef __hip_bfloat16 bf16;
typedef __attribute__((ext_vector_type(8))) short short8;   // 8 bf16 = 4 VGPRs
typedef __attribute__((ext_vector_type(4))) float float4v;  // MFMA C/D
typedef __attribute__((ext_vector_type(4))) short short4v;

__device__ __forceinline__ short f2bs(float x) {
    bf16 b = __float2bfloat16(x);
    return *reinterpret_cast<short*>(&b);
}
__device__ __forceinline__ float bs2f(short s) {
    bf16 b = *reinterpret_cast<bf16*>(&s);
    return __bfloat162float(b);
}

#define GLL16(g, l) __builtin_amdgcn_global_load_lds(                      \
    (const __attribute__((address_space(1))) void*)(g),                    \
    (__attribute__((address_space(3))) void*)(l), 16, 0, 0)

// ---------------- preprocessing: f32 -> padded bf16 layouts ----------------

// emb (50000,300) f32 -> emb_bf (50000,320) bf16, zero pad. 4 shorts/thread.
__global__ __launch_bounds__(256) void conv_emb(
    const float* __restrict__ src, short* __restrict__ dst)
{
    const int idx = blockIdx.x * 256 + threadIdx.x;      // 50000*80
    if (idx >= 50000 * 80) return;
    const int row = idx / 80;
    const int k4  = (idx - row * 80) * 4;
    short4v v;
#pragma unroll
    for (int j = 0; j < 4; ++j)
        v[j] = (k4 + j < 300) ? f2bs(src[(long)row * 300 + k4 + j]) : (short)0;
    *(short4v*)&dst[(long)row * 320 + k4] = v;
}

// W_leaf (300,300) -> Bleaf (320,320) bf16 zero-padded
__global__ __launch_bounds__(256) void conv_wleaf(
    const float* __restrict__ src, short* __restrict__ dst)
{
    const int idx = blockIdx.x * 256 + threadIdx.x;      // 320*320
    if (idx >= 320 * 320) return;
    const int row = idx / 320, k = idx - row * 320;
    dst[idx] = (row < 300 && k < 300) ? f2bs(src[row * 300 + k]) : (short)0;
}

// W_h (300,600) -> Bh (320,640): k'<300 -> k'; 320<=k'<620 -> k'-20; else 0
__global__ __launch_bounds__(256) void conv_wh(
    const float* __restrict__ src, short* __restrict__ dst)
{
    const int idx = blockIdx.x * 256 + threadIdx.x;      // 320*640
    if (idx >= 320 * 640) return;
    const int row = idx / 640, k = idx - row * 640;
    float v = 0.f;
    if (row < 300) {
        if (k < 300)                 v = src[row * 600 + k];
        else if (k >= 320 && k < 620) v = src[row * 600 + k - 20];
    }
    dst[idx] = f2bs(v);
}

// b_h (300,) -> biasp (320,) f32 zero-padded
__global__ __launch_bounds__(320) void conv_bias(
    const float* __restrict__ src, float* __restrict__ dst)
{
    const int i = threadIdx.x;
    if (i < 320) dst[i] = (i < 300) ? src[i] : 0.f;
}

// ---------------- MFMA GEMM (2-phase prefetch, counted vmcnt) ----------------
// out(M,320 bf16) = X(M,KE bf16) @ Wp(320,KE bf16)^T (+ biasp), KE in {320,640}.
// GMODE 0: X read directly from Xsrc rows.
// GMODE 2 (KE=640 only): A-row m = concat(Hv[wid[2m]], Hv[wid[2m+1]]) gathered.
// Block: 256 thr = 4 waves 2x2; tile M=128 x N=320. Wave: 64x160.
// Pipeline: double-buffered LDS; chunk k+1's 7 global_load_lds issued BEFORE
// computing chunk k; s_waitcnt vmcnt(7) (never 0 mid-loop) + raw s_barrier.
// Per-chunk critical path drops from (load_lat + compute) to ~max of the two.
template <int KE, int GMODE, bool BIAS>
__global__ __launch_bounds__(256, 2) void mfma_gemm(
    const short* __restrict__ Xsrc, const int* __restrict__ wid,
    const short* __restrict__ emb, const short* __restrict__ Wp,
    const float* __restrict__ biasp, short* __restrict__ out)
{
    static_assert(GMODE != 2 || KE == 640, "pair-gather requires KE=640");
    __shared__ __align__(16) short As[2][128 * 32];   // 2 x 8 KB
    __shared__ __align__(16) short Bs[2][320 * 32];   // 2 x 20 KB -> 57,344 B

    const int tid  = threadIdx.x;
    const int lane = tid & 63;
    const int w    = tid >> 6;
    const int wm   = w >> 1, wn = w & 1;
    const long m0  = (long)blockIdx.x * 128;

    const int s_q   = lane & 3;     // this lane's LDS k-quarter slot
    const int r_off = lane >> 2;    // row within 16-row staging group

    // staging global pointers (chunk-invariant bases)
    const char* gL[2];
    const char* gR[2];
#pragma unroll
    for (int j = 0; j < 2; ++j) {
        const int r = (w * 2 + j) * 16 + r_off;            // 0..127
        const int q = s_q ^ ((r >> 1) & 3);                // global k-quarter
        if (GMODE == 2) {
            const long node = m0 + r;
            gL[j] = (const char*)emb + (long)wid[2 * node]     * 640 + q * 16;
            gR[j] = (const char*)emb + (long)wid[2 * node + 1] * 640 + q * 16;
        } else {
            gL[j] = (const char*)Xsrc + (m0 + r) * (long)(KE * 2) + q * 16;
            gR[j] = gL[j];
        }
    }
    const char* gB[5];
#pragma unroll
    for (int j = 0; j < 5; ++j) {
        const int r = (w * 5 + j) * 16 + r_off;            // 0..319
        const int q = s_q ^ ((r >> 1) & 3);
        gB[j] = (const char*)Wp + r * (long)(KE * 2) + q * 16;
    }

    // fragment LDS offsets (element units, buffer-invariant)
    int oA[4];
#pragma unroll
    for (int t = 0; t < 4; ++t) {
        const int row = wm * 64 + t * 16 + (lane & 15);
        const int s   = (lane >> 4) ^ ((row >> 1) & 3);
        oA[t] = row * 32 + s * 8;
    }
    int oB[10];
#pragma unroll
    for (int u = 0; u < 10; ++u) {
        const int n = wn * 160 + u * 16 + (lane & 15);
        const int s = (lane >> 4) ^ ((n >> 1) & 3);
        oB[u] = n * 32 + s * 8;
    }

    // stage chunk kc into buffer buf (7 x global_load_lds, wave-uniform dest)
    auto stage = [&](int buf, int kc) {
        char* baseA = (char*)&As[buf][0];
        char* baseB = (char*)&Bs[buf][0];
        if (GMODE == 2) {
            // chunks 0..9 = left gathered row, 10..19 = right gathered row
            const bool lft = (kc < 10);
            const int off = (lft ? kc : kc - 10) * 64;
            GLL16((lft ? gL[0] : gR[0]) + off, baseA + (w * 2 + 0) * 1024);
            GLL16((lft ? gL[1] : gR[1]) + off, baseA + (w * 2 + 1) * 1024);
        } else {
            const int off = kc * 64;
            GLL16(gL[0] + off, baseA + (w * 2 + 0) * 1024);
            GLL16(gL[1] + off, baseA + (w * 2 + 1) * 1024);
        }
        const int offb = kc * 64;
#pragma unroll
        for (int j = 0; j < 5; ++j)
            GLL16(gB[j] + offb, baseB + (w * 5 + j) * 1024);
    };

    float4v acc[4][10];
#pragma unroll
    for (int t = 0; t < 4; ++t)
#pragma unroll
        for (int u = 0; u < 10; ++u) acc[t][u] = (float4v)0.f;

    const int NCH = KE / 32;
    stage(0, 0);                           // prologue: chunk 0 in flight
    for (int kc = 0; kc < NCH; ++kc) {
        const int cur = kc & 1;
        if (kc + 1 < NCH) {
            stage(cur ^ 1, kc + 1);        // next chunk's 7 loads in flight
            // wait only for chunk kc's 7 loads (the 7 newest stay in flight)
            asm volatile("s_waitcnt vmcnt(7)" ::: "memory");
        } else {
            asm volatile("s_waitcnt vmcnt(0)" ::: "memory");
        }
        __builtin_amdgcn_s_barrier();      // all waves' chunk-kc stores landed
        asm volatile("" ::: "memory");     // keep ds_reads below the barrier
        __builtin_amdgcn_sched_barrier(0);

        const short* bA = &As[cur][0];
        const short* bB = &Bs[cur][0];
        short8 a[4], b[10];
#pragma unroll
        for (int t = 0; t < 4; ++t) a[t] = *(const short8*)(bA + oA[t]);
#pragma unroll
        for (int u = 0; u < 10; ++u) b[u] = *(const short8*)(bB + oB[u]);
#pragma unroll
        for (int u = 0; u < 10; ++u)
#pragma unroll
            for (int t = 0; t < 4; ++t)
                acc[t][u] = __builtin_amdgcn_mfma_f32_16x16x32_bf16(
                    a[t], b[u], acc[t][u], 0, 0, 0);
        __builtin_amdgcn_s_barrier();      // reads of buf[cur] done -> chunk
                                           // kc+2 may overwrite it next iter
    }

    // epilogue: C/D layout col=lane&15, row=(lane>>4)*4+reg
#pragma unroll
    for (int u = 0; u < 10; ++u) {
        const int c = wn * 160 + u * 16 + (lane & 15);
        const float bv = BIAS ? biasp[c] : 0.f;
#pragma unroll
        for (int t = 0; t < 4; ++t) {
            const long mb = m0 + wm * 64 + t * 16 + (lane >> 4) * 4;
#pragma unroll
            for (int r4 = 0; r4 < 4; ++r4)
                out[(mb + r4) * 320 + c] = f2bs(acc[t][u][r4] + bv);
        }
    }
}

// ---------------- classifier ----------------
// roots: 512 rows of 640 bf16 (pads at 300..320, 620..640). One wave per row.
__global__ __launch_bounds__(64) void cls_kernel(
    const short* __restrict__ roots, const float* __restrict__ W_cls,
    const float* __restrict__ b_cls, float* __restrict__ out)
{
    const int b    = blockIdx.x;
    const int lane = threadIdx.x;
    const short* row = roots + (long)b * 640;

    float a0 = 0.f, a1 = 0.f, a2 = 0.f;
#pragma unroll
    for (int i = 0; i < 10; ++i) {
        const int k = lane + 64 * i;
        if (k < 600) {
            const int col = (k < 300) ? k : k + 20;
            const float f = 1.f / (1.f + __expf(-bs2f(row[col])));
            a0 += f * W_cls[k];
            a1 += f * W_cls[600 + k];
            a2 += f * W_cls[1200 + k];
        }
    }
#pragma unroll
    for (int off = 32; off > 0; off >>= 1) {
        a0 += __shfl_down(a0, off);
        a1 += __shfl_down(a1, off);
        a2 += __shfl_down(a2, off);
    }
    if (lane == 0) {
        const float l0 = a0 + b_cls[0];
        const float l1 = a1 + b_cls[1];
        const float l2 = a2 + b_cls[2];
        const float m  = fmaxf(l0, fmaxf(l1, l2));
        const float s  = __expf(l0 - m) + __expf(l1 - m) + __expf(l2 - m);
        const float ls = m + __logf(s);
        out[b * 3 + 0] = l0 - ls;
        out[b * 3 + 1] = l1 - ls;
        out[b * 3 + 2] = l2 - ls;
    }
}

extern "C" void kernel_launch(void* const* d_in, const int* in_sizes, int n_in,
                              void* d_out, int out_size, void* d_ws, size_t ws_size,
                              hipStream_t stream)
{
    const int*   wid    = (const int*)d_in[0];     // (512,2,256) int32
    const float* emb    = (const float*)d_in[1];   // (50000,300) f32
    const float* W_leaf = (const float*)d_in[2];   // (300,300)
    const float* W_h    = (const float*)d_in[3];   // (300,600)
    const float* b_h    = (const float*)d_in[4];   // (300,)
    const float* W_cls  = (const float*)d_in[5];   // (3,600)
    const float* b_cls  = (const float*)d_in[6];   // (3,)
    float* outp = (float*)d_out;                   // (512,3) f32

    (void)in_sizes; (void)n_in; (void)out_size; (void)ws_size;

    // ws layout (peak 158,475,520 B):
    //   bufA   @ 0           : 131072*320*2 =  83,886,080  (tree ping)
    //   bufB   @  83,886,080 :  65536*320*2 =  41,943,040  (tree pong)
    //   emb_bf @  83,886,080 : 50048*320*2  =  32,030,720  (ALIASES bufB: dead
    //            after Hv GEMM; bufB first written at L2, which runs later)
    //   Hv     @ 125,829,120 : 50048*320*2  =  32,030,720  (vocab leaf hidden)
    //   Bleaf  @ 157,859,840 : 320*320*2    =     204,800
    //   Bh     @ 158,064,640 : 320*640*2    =     409,600
    //   biasp  @ 158,474,240 : 320*4        =       1,280
    char* ws = (char*)d_ws;
    short* bufA   = (short*)(ws);
    short* bufB   = (short*)(ws + 83886080);
    short* emb_bf = (short*)(ws + 83886080);
    short* Hv     = (short*)(ws + 125829120);
    short* Bleaf  = (short*)(ws + 157859840);
    short* Bh     = (short*)(ws + 158064640);
    float* biasp  = (float*)(ws + 158474240);

    conv_emb  <<<(50000 * 80 + 255) / 256, 256, 0, stream>>>(emb, emb_bf);
    conv_wleaf<<<(320 * 320) / 256, 256, 0, stream>>>(W_leaf, Bleaf);
    conv_wh   <<<(320 * 640) / 256, 256, 0, stream>>>(W_h, Bh);
    conv_bias <<<1, 320, 0, stream>>>(b_h, biasp);

    // Vocab-level leaf transform: Hv = emb_bf @ Bleaf^T, M=50048 (391 blocks).
    mfma_gemm<320, 0, false><<<50048 / 128, 256, 0, stream>>>(
        emb_bf, nullptr, nullptr, Bleaf, biasp, Hv);

    // L1: node m = W_h @ concat(Hv[wid[2m]], Hv[wid[2m+1]]) + b_h.
    mfma_gemm<640, 2, true><<<131072 / 128, 256, 0, stream>>>(
        nullptr, wid, Hv, Bh, biasp, bufA);

    // L2..L8: node m reads prev rows 2m,2m+1 = contiguous 640 bf16 (pads align
    // with Bh's zero k-columns). Ping-pong bufA <-> bufB.
    short* cur = bufA;
    short* nxt = bufB;
    int nodes = 65536;
    for (int l = 0; l < 7; ++l) {
        mfma_gemm<640, 0, true><<<nodes / 128, 256, 0, stream>>>(
            cur, nullptr, nullptr, Bh, biasp, nxt);
        short* t = cur; cur = nxt; nxt = t;
        nodes >>= 1;
    }
    // roots: cur holds 1024 rows x 320 -> 512 x 640 view

    cls_kernel<<<512, 64, 0, stream>>>(cur, W_cls, b_cls, outp);
}